// Round 18
// baseline (200.060 us; speedup 1.0000x reference)
//
#include <hip/hip_runtime.h>
#include <math.h>

#define NN 6000
#define NE 12000
#define DCAP 32
// HC=128, H=4, D=32

typedef _Float16 f16;
typedef _Float16 f16x8 __attribute__((ext_vector_type(8)));
typedef unsigned short u16x8 __attribute__((ext_vector_type(8)));
typedef float f32x4 __attribute__((ext_vector_type(4)));

__device__ __forceinline__ float gelu_f(float x) {
    return 0.5f * x * (1.0f + erff(x * 0.70710678118654752f));
}

// ---------------- merged preamble ----------------
// blocks [0,512): pre_bmat -> fragment-major single-f16 BF
// blocks [512,3512): node_enc; [3512,3559): bucket; [3559,3566): pre_ew; [3566,3574): split_gat
// requires CNT pre-zeroed.
__global__ __launch_bounds__(256) void k_pre_all(
    const float* __restrict__ nn_w, const float* __restrict__ nn_b,
    const float* __restrict__ nn_root, f16* __restrict__ bfh,
    const float* __restrict__ x, const float* __restrict__ node_w,
    float* __restrict__ h0, f16* __restrict__ hf,
    const int* __restrict__ ei, const float* __restrict__ eattr,
    int* __restrict__ cnt, float* __restrict__ ebs,
    const float* __restrict__ gat_e_w, const float* __restrict__ eew,
    const float* __restrict__ eeb, const float* __restrict__ lb,
    const float* __restrict__ rb, float* __restrict__ EW, float* __restrict__ biasLR,
    const float* __restrict__ gwl, const float* __restrict__ gwr,
    f16* __restrict__ WTh)
{
    __shared__ float enc[5][128];
    int b = blockIdx.x;
    int tid = threadIdx.x;
    if (b < 512) {
        for (int l = tid; l < 640; l += 256) {
            int j = l >> 7, k = l & 127;
            enc[j][k] = (j < 4) ? eew[j * 128 + k] : eeb[k];
        }
        __syncthreads();
        int gid = b * 256 + tid;            // 8 * 16384 total
        int i = gid >> 14;
        int col = gid & 16383;              // k_in*128 + o
        int k_in = col >> 7, o = col & 127;
        const float* w = nn_w + (size_t)i * (128 * 16384) + col;
        float a0 = 0.f, a1 = 0.f, a2 = 0.f, a3 = 0.f, a4 = 0.f;
        #pragma unroll 8
        for (int k = 0; k < 128; ++k) {
            float wv = w[(size_t)k * 16384];
            a0 += enc[0][k] * wv; a1 += enc[1][k] * wv; a2 += enc[2][k] * wv;
            a3 += enc[3][k] * wv; a4 += enc[4][k] * wv;
        }
        a4 += nn_b[i * 16384 + col];
        float root = nn_root[(size_t)i * 16384 + col];
        float vals[6] = {a0, a1, a2, a3, a4, root};
        int ot = o >> 4, l15o = o & 15;
        size_t base_i = ((size_t)i * 8 + ot) * 24;
        #pragma unroll
        for (int j = 0; j < 6; ++j) {
            int c = j * 128 + k_in;
            int kb = c >> 5, lg = (c >> 3) & 3, jj = c & 7;
            size_t dst = ((base_i + kb) * 64 + lg * 16 + l15o) * 8 + jj;
            bfh[dst] = (f16)vals[j];
        }
    } else if (b < 3512) {
        int idx = (b - 512) * 256 + tid;
        int n = idx >> 7, c = idx & 127;
        float s = 0.f;
        #pragma unroll
        for (int f = 0; f < 6; ++f) s += x[n * 6 + f] * node_w[f * 128 + c];
        h0[idx] = s;
        hf[idx] = (f16)s;
    } else if (b < 3559) {
        int e = (b - 3512) * 256 + tid;
        if (e < NE) {
            int d = ei[NE + e];
            int pos = atomicAdd(&cnt[d], 1);
            if (pos < DCAP) {
                float* p = ebs + (size_t)(d * DCAP + pos) * 8;
                p[0] = __int_as_float(ei[e]);
                p[1] = eattr[e * 4 + 0];
                p[2] = eattr[e * 4 + 1];
                p[3] = eattr[e * 4 + 2];
                p[4] = eattr[e * 4 + 3];
            }
        }
    } else if (b < 3566) {
        int idx = (b - 3559) * 256 + tid;
        if (idx < 1280) {
            int i = idx / 640; int r = idx % 640; int j = r >> 7; int o = r & 127;
            float s = 0.f;
            for (int k = 0; k < 128; ++k) {
                float e = (j < 4) ? eew[j * 128 + k] : eeb[k];
                s += e * gat_e_w[i * 16384 + k * 128 + o];
            }
            EW[idx] = s;
        } else if (idx < 1792) {
            int j = idx - 1280; int i = j >> 8; int c = j & 255;
            biasLR[j] = (c < 128) ? lb[i * 128 + c] : rb[i * 128 + c - 128];
        }
    } else {
        int bb = b - 3566;              // 0..7
        int i = bb >> 2, half = (bb >> 1) & 1, piece = bb & 1;
        const float* s = (half ? gwr : gwl) + (size_t)i * 16384;
        size_t dbase = (size_t)i * 32768 + (size_t)half * 16384;
        for (int l = tid + piece * 8192; l < 8192 + piece * 8192; l += 256) {
            int o = l >> 7, k = l & 127;
            WTh[dbase + o * 128 + k] = (f16)s[k * 128 + o];
        }
    }
}

// ---------------- MFMA matmul (GAT): C[M,P](f16) = A_f16 @ B^T + bias ----------------
__global__ __launch_bounds__(256) void k_mm16(
    const f16* __restrict__ A, const f16* __restrict__ Bh,
    const float* __restrict__ bias, f16* __restrict__ C, int M, int P)
{
    __shared__ __align__(16) unsigned short smem[16384];   // 32KB: sA|sBh
    unsigned short* sA  = smem;
    unsigned short* sBh = smem + 8192;
    const int tid = threadIdx.x;
    const int r0 = blockIdx.x * 64, n0 = blockIdx.y * 64;
    #pragma unroll
    for (int i = 0; i < 4; ++i) {
        int g = tid + i * 256; int row = g >> 4, u = g & 15;
        int dst = row * 128 + ((u ^ (row & 7)) << 3);
        int r = r0 + row;
        if (r < M) *(u16x8*)&sA[dst] = *(const u16x8*)((const unsigned short*)A + (size_t)r * 128 + u * 8);
        else { u16x8 z; for (int j = 0; j < 8; ++j) z[j] = 0; *(u16x8*)&sA[dst] = z; }
        size_t sb = (size_t)(n0 + row) * 128 + u * 8;
        *(u16x8*)&sBh[dst] = *(const u16x8*)((const unsigned short*)Bh + sb);
    }
    __syncthreads();
    const int lane = tid & 63, wid = tid >> 6;
    const int wm = wid & 1, wn = wid >> 1;
    const int l15 = lane & 15, lg = lane >> 4;
    f32x4 acc[2][2] = {};
    #pragma unroll
    for (int kk = 0; kk < 4; ++kk) {
        f16x8 a[2], bh_[2];
        #pragma unroll
        for (int fm = 0; fm < 2; ++fm) {
            int row = wm * 32 + fm * 16 + l15;
            int off = row * 128 + ((((kk << 2) + lg) ^ (row & 7)) << 3);
            a[fm] = *(const f16x8*)&sA[off];
        }
        #pragma unroll
        for (int fn = 0; fn < 2; ++fn) {
            int row = wn * 32 + fn * 16 + l15;
            int off = row * 128 + ((((kk << 2) + lg) ^ (row & 7)) << 3);
            bh_[fn] = *(const f16x8*)&sBh[off];
        }
        #pragma unroll
        for (int fm = 0; fm < 2; ++fm)
        #pragma unroll
        for (int fn = 0; fn < 2; ++fn)
            acc[fm][fn] = __builtin_amdgcn_mfma_f32_16x16x32_f16(a[fm], bh_[fn], acc[fm][fn], 0, 0, 0);
    }
    #pragma unroll
    for (int fn = 0; fn < 2; ++fn) {
        int col = n0 + wn * 32 + fn * 16 + l15;
        float bv = bias ? bias[col] : 0.f;
        #pragma unroll
        for (int fm = 0; fm < 2; ++fm) {
            int rbase = r0 + wm * 32 + fm * 16 + lg * 4;
            #pragma unroll
            for (int j = 0; j < 4; ++j) {
                int r = rbase + j;
                if (r < M) C[(size_t)r * P + col] = (f16)(acc[fm][fn][j] + bv);
            }
        }
    }
}

// ---------------- fused GATv2 layer (f16 XLXR, batched loads + deg<=4 register cache) ----------------
__global__ __launch_bounds__(256) void k_gat_fused(
    const f16* __restrict__ XLXR, const float* __restrict__ ebs,
    const int* __restrict__ cnt, const float* __restrict__ EW,
    const float* __restrict__ att, float* __restrict__ h0,
    const float* __restrict__ bias, const float* __restrict__ g,
    const float* __restrict__ b,
    f16* __restrict__ hf)
{
    __shared__ float slog[4][DCAP][4];
    __shared__ float sms[4][4][2];
    int rowl = threadIdx.x >> 6, lane = threadIdx.x & 63;
    int r = blockIdx.x * 4 + rowl;
    int deg = cnt[r]; if (deg > DCAP) deg = DCAP;
    int dc = (deg < 4) ? deg : 4;
    float hz0 = h0[r * 128 + lane], hz1 = h0[r * 128 + 64 + lane];
    float xr0 = (float)XLXR[r * 256 + 128 + lane];
    float xr1 = (float)XLXR[r * 256 + 192 + lane];
    float e0 = EW[lane], e1 = EW[128 + lane], e2 = EW[256 + lane], e3 = EW[384 + lane], e4 = EW[512 + lane];
    float f0 = EW[64 + lane], f1 = EW[192 + lane], f2 = EW[320 + lane], f3 = EW[448 + lane], f4 = EW[576 + lane];
    float at0 = att[lane], at1 = att[64 + lane];
    f32x4 q[4]; float a3v[4]; float xs0[4], xs1[4];
    #pragma unroll
    for (int j = 0; j < 4; ++j) {
        if (j < dc) {
            const float* ep = ebs + (size_t)(r * DCAP + j) * 8;
            q[j] = *(const f32x4*)ep;
            a3v[j] = ep[4];
        }
    }
    #pragma unroll
    for (int j = 0; j < 4; ++j) {
        if (j < dc) {
            int s = __float_as_int(q[j][0]);
            xs0[j] = (float)XLXR[s * 256 + lane];
            xs1[j] = (float)XLXR[s * 256 + 64 + lane];
        }
    }
    #pragma unroll
    for (int j = 0; j < 4; ++j) {
        if (j < dc) {
            float a0 = q[j][1], a1 = q[j][2], a2 = q[j][3], a3 = a3v[j];
            float g0 = xs0[j] + xr0 + (a0 * e0 + a1 * e1 + a2 * e2 + a3 * e3 + e4);
            float g1 = xs1[j] + xr1 + (a0 * f0 + a1 * f1 + a2 * f2 + a3 * f3 + f4);
            g0 = (g0 > 0.f) ? g0 : 0.1f * g0;
            g1 = (g1 > 0.f) ? g1 : 0.1f * g1;
            float p0 = g0 * at0, p1 = g1 * at1;
            for (int o = 16; o; o >>= 1) { p0 += __shfl_xor(p0, o, 32); p1 += __shfl_xor(p1, o, 32); }
            if ((lane & 31) == 0) {
                int hh2 = lane >> 5;
                slog[rowl][j][hh2] = p0;
                slog[rowl][j][2 + hh2] = p1;
            }
        }
    }
    for (int k = 4; k < deg; ++k) {
        const float* ep = ebs + (size_t)(r * DCAP + k) * 8;
        f32x4 qq = *(const f32x4*)ep;
        float a3 = ep[4];
        int s = __float_as_int(qq[0]);
        float a0 = qq[1], a1 = qq[2], a2 = qq[3];
        float g0 = (float)XLXR[s * 256 + lane]      + xr0 + (a0 * e0 + a1 * e1 + a2 * e2 + a3 * e3 + e4);
        float g1 = (float)XLXR[s * 256 + 64 + lane] + xr1 + (a0 * f0 + a1 * f1 + a2 * f2 + a3 * f3 + f4);
        g0 = (g0 > 0.f) ? g0 : 0.1f * g0;
        g1 = (g1 > 0.f) ? g1 : 0.1f * g1;
        float p0 = g0 * at0, p1 = g1 * at1;
        for (int o = 16; o; o >>= 1) { p0 += __shfl_xor(p0, o, 32); p1 += __shfl_xor(p1, o, 32); }
        if ((lane & 31) == 0) {
            int hh2 = lane >> 5;
            slog[rowl][k][hh2] = p0;
            slog[rowl][k][2 + hh2] = p1;
        }
    }
    if (lane < 4) {
        float mh = -1e30f;
        for (int k = 0; k < deg; ++k) mh = fmaxf(mh, slog[rowl][k][lane]);
        float sh = 0.f;
        for (int k = 0; k < deg; ++k) sh += expf(slog[rowl][k][lane] - mh);
        sms[rowl][lane][0] = mh; sms[rowl][lane][1] = sh;
    }
    int hd = lane >> 5;
    float m0 = sms[rowl][hd][0], s0 = sms[rowl][hd][1];
    float m1 = sms[rowl][2 + hd][0], s1 = sms[rowl][2 + hd][1];
    float acc0 = 0.f, acc1 = 0.f;
    #pragma unroll
    for (int j = 0; j < 4; ++j) {
        if (j < dc) {
            float al0 = expf(slog[rowl][j][hd] - m0) / (s0 + 1e-16f);
            float al1 = expf(slog[rowl][j][2 + hd] - m1) / (s1 + 1e-16f);
            acc0 += al0 * xs0[j];
            acc1 += al1 * xs1[j];
        }
    }
    for (int k = 4; k < deg; ++k) {
        int s = __float_as_int(ebs[(size_t)(r * DCAP + k) * 8]);
        float al0 = expf(slog[rowl][k][hd] - m0) / (s0 + 1e-16f);
        float al1 = expf(slog[rowl][k][2 + hd] - m1) / (s1 + 1e-16f);
        acc0 += al0 * (float)XLXR[s * 256 + lane];
        acc1 += al1 * (float)XLXR[s * 256 + 64 + lane];
    }
    float v0 = hz0 + acc0 + bias[lane];
    float v1 = hz1 + acc1 + bias[64 + lane];
    float sum = v0 + v1;
    for (int o = 32; o; o >>= 1) sum += __shfl_xor(sum, o, 64);
    float mean = sum * 0.0078125f;
    float d0 = v0 - mean, d1 = v1 - mean;
    float var = d0 * d0 + d1 * d1;
    for (int o = 32; o; o >>= 1) var += __shfl_xor(var, o, 64);
    float inv = rsqrtf(var * 0.0078125f + 1e-5f);
    float y0 = gelu_f(d0 * inv * g[lane] + b[lane]);
    float y1 = gelu_f(d1 * inv * g[64 + lane] + b[64 + lane]);
    h0[r * 128 + lane] = y0; h0[r * 128 + 64 + lane] = y1;
    hf[r * 128 + lane] = (f16)y0;
    hf[r * 128 + 64 + lane] = (f16)y1;
}

// ---------------- fused NNConv layer (BM=4, grid 1500, 256 thr), single-f16 B ----------------
// 4 waves; wave w owns dst row r0+w (single 2-level gather chain) and computes
// col tiles {2w, 2w+1}. MFMA duplicate-row trick: lane reads A row (l15&3);
// C rows 4..15 are garbage and never stored. LDS 6KB.
__global__ __launch_bounds__(256) void k_conv(
    const float* __restrict__ ebs, const int* __restrict__ cnt,
    const f16* __restrict__ TF,
    const f16* __restrict__ BFh,
    const float* __restrict__ bias,
    const float* __restrict__ h0, float* __restrict__ HIN,
    const float* __restrict__ lng, const float* __restrict__ lnb,
    f16* __restrict__ TFout, int kind,
    const float* __restrict__ outw, const float* __restrict__ outb,
    float* __restrict__ outp)
{
    __shared__ __align__(16) unsigned short sA[4 * 768];    // 6KB
    const int tid = threadIdx.x;
    const int r0 = blockIdx.x * 4;
    const int lane = tid & 63, w = tid >> 6;
    const int l15 = lane & 15, lg = lane >> 4;

    // ---- phase 1: single-row batched gather + epilogue prefetch ----
    int r = r0 + w;                                  // < 6000 always (grid 1500*4)
    int deg = cnt[r]; if (deg > DCAP) deg = DCAP;
    float bs0 = bias[lane], bs1 = bias[64 + lane];
    float lg0 = lng[lane], lg1 = lng[64 + lane];
    float lb0 = lnb[lane], lb1 = lnb[64 + lane];
    float h00 = 0.f, h01 = 0.f, hi0 = 0.f, hi1 = 0.f;
    if (kind != 2) {
        h00 = h0[r * 128 + lane];
        h01 = h0[r * 128 + 64 + lane];
    }
    if (kind != 0) {
        hi0 = HIN[r * 128 + lane];
        hi1 = HIN[r * 128 + 64 + lane];
    }
    unsigned int rtv = *(const unsigned int*)&TF[(size_t)r * 128 + lane * 2];
    float acc[5][2] = {};
    for (int k0 = 0; k0 < deg; k0 += 4) {
        int km = deg - k0; if (km > 4) km = 4;
        f32x4 q[4]; float a3v[4]; unsigned int tt[4];
        #pragma unroll
        for (int j = 0; j < 4; ++j) {
            if (j < km) {
                const float* ep = ebs + (size_t)(r * DCAP + k0 + j) * 8;
                q[j] = *(const f32x4*)ep;
                a3v[j] = ep[4];
            }
        }
        #pragma unroll
        for (int j = 0; j < 4; ++j) {
            if (j < km) {
                int s = __float_as_int(q[j][0]);
                tt[j] = *(const unsigned int*)&TF[(size_t)s * 128 + lane * 2];
            }
        }
        #pragma unroll
        for (int j = 0; j < 4; ++j) {
            if (j < km) {
                float a0 = q[j][1], a1 = q[j][2], a2 = q[j][3], a3 = a3v[j];
                float t0 = (float)__builtin_bit_cast(f16, (unsigned short)(tt[j] & 0xffff));
                float t1 = (float)__builtin_bit_cast(f16, (unsigned short)(tt[j] >> 16));
                acc[0][0] += a0 * t0; acc[1][0] += a1 * t0; acc[2][0] += a2 * t0;
                acc[3][0] += a3 * t0; acc[4][0] += t0;
                acc[0][1] += a0 * t1; acc[1][1] += a1 * t1; acc[2][1] += a2 * t1;
                acc[3][1] += a3 * t1; acc[4][1] += t1;
            }
        }
    }
    {
        int row = w;                     // 0..3; rw = row&7 = row
        #pragma unroll
        for (int j = 0; j < 5; ++j) {
            int u = j * 16 + (lane >> 2);
            int us = (u & ~7) | ((u & 7) ^ row);
            unsigned short p0 = __builtin_bit_cast(unsigned short, (f16)acc[j][0]);
            unsigned short p1 = __builtin_bit_cast(unsigned short, (f16)acc[j][1]);
            *(unsigned int*)&sA[row * 768 + us * 8 + ((2 * lane) & 7)] =
                (unsigned int)p0 | ((unsigned int)p1 << 16);
        }
        int u = 80 + (lane >> 2);
        int us = (u & ~7) | ((u & 7) ^ row);
        *(unsigned int*)&sA[row * 768 + us * 8 + ((2 * lane) & 7)] = rtv;
    }
    __syncthreads();

    // ---- phase 2: MFMA, wave w -> col tiles {2w, 2w+1}; A row = l15&3 (dup trick) ----
    f32x4 acc2[2] = {};
    const f16* bhp0 = BFh + ((size_t)(2 * w) * 24) * 512 + (size_t)lane * 8;
    const f16* bhp1 = bhp0 + (size_t)24 * 512;
    #pragma unroll
    for (int kb = 0; kb < 24; ++kb) {
        int row = l15 & 3;
        int u = kb * 4 + lg;
        int us = (u & ~7) | ((u & 7) ^ row);
        f16x8 a = *(const f16x8*)&sA[row * 768 + us * 8];
        f16x8 b0 = *(const f16x8*)(bhp0 + (size_t)kb * 512);
        f16x8 b1 = *(const f16x8*)(bhp1 + (size_t)kb * 512);
        acc2[0] = __builtin_amdgcn_mfma_f32_16x16x32_f16(a, b0, acc2[0], 0, 0, 0);
        acc2[1] = __builtin_amdgcn_mfma_f32_16x16x32_f16(a, b1, acc2[1], 0, 0, 0);
    }
    __syncthreads();
    float* sOut = (float*)sA;   // 4 x 132 f32, aliases sA
    #pragma unroll
    for (int t = 0; t < 2; ++t) {
        int col = (2 * w + t) * 16 + l15;
        if (lg == 0) {
            #pragma unroll
            for (int j = 0; j < 4; ++j)
                sOut[j * 132 + col] = acc2[t][j];
        }
    }
    __syncthreads();

    // ---- phase 3: epilogue, wave w -> its own row (prefetched inputs) ----
    {
        float c0 = bs0 + sOut[w * 132 + lane];
        float c1 = bs1 + sOut[w * 132 + 64 + lane];
        float u0, u1;
        if (kind == 0) {
            u0 = h00 + c0;
            u1 = h01 + c1;
            HIN[r * 128 + lane] = u0; HIN[r * 128 + 64 + lane] = u1;
        } else if (kind == 1) {
            u0 = hi0 + h00 + c0;
            u1 = hi1 + h01 + c1;
            HIN[r * 128 + lane] = u0; HIN[r * 128 + 64 + lane] = u1;
        } else {
            u0 = hi0 + c0;
            u1 = hi1 + c1;
        }
        float sum = u0 + u1;
        for (int o = 32; o; o >>= 1) sum += __shfl_xor(sum, o, 64);
        float mean = sum * 0.0078125f;
        float d0 = u0 - mean, d1 = u1 - mean;
        float var = d0 * d0 + d1 * d1;
        for (int o = 32; o; o >>= 1) var += __shfl_xor(var, o, 64);
        float inv = rsqrtf(var * 0.0078125f + 1e-5f);
        float y0 = gelu_f(d0 * inv * lg0 + lb0);
        float y1 = gelu_f(d1 * inv * lg1 + lb1);
        if (kind != 2) {
            TFout[r * 128 + lane] = (f16)y0;
            TFout[r * 128 + 64 + lane] = (f16)y1;
        } else {
            float p0 = y0 * outw[lane * 2 + 0] + y1 * outw[(64 + lane) * 2 + 0];
            float p1 = y0 * outw[lane * 2 + 1] + y1 * outw[(64 + lane) * 2 + 1];
            for (int o = 32; o; o >>= 1) { p0 += __shfl_xor(p0, o, 64); p1 += __shfl_xor(p1, o, 64); }
            if (lane == 0) {
                outp[r * 2 + 0] = p0 + outb[0];
                outp[r * 2 + 1] = p1 + outb[1];
            }
        }
    }
}

extern "C" void kernel_launch(void* const* d_in, const int* in_sizes, int n_in,
                              void* d_out, int out_size, void* d_ws, size_t ws_size,
                              hipStream_t stream)
{
    const float* x        = (const float*)d_in[0];
    const int*   ei       = (const int*)d_in[1];
    const float* eattr    = (const float*)d_in[2];
    const float* node_w   = (const float*)d_in[4];
    const float* eew      = (const float*)d_in[5];
    const float* eeb      = (const float*)d_in[6];
    const float* gat_l_w  = (const float*)d_in[7];
    const float* gat_l_b  = (const float*)d_in[8];
    const float* gat_r_w  = (const float*)d_in[9];
    const float* gat_r_b  = (const float*)d_in[10];
    const float* gat_e_w  = (const float*)d_in[11];
    const float* gat_att  = (const float*)d_in[12];
    const float* gat_bias = (const float*)d_in[13];
    const float* gat_ln_g = (const float*)d_in[14];
    const float* gat_ln_b = (const float*)d_in[15];
    const float* nn_w     = (const float*)d_in[16];
    const float* nn_b     = (const float*)d_in[17];
    const float* nn_root  = (const float*)d_in[18];
    const float* nn_bias  = (const float*)d_in[19];
    const float* dec_g    = (const float*)d_in[20];
    const float* dec_b    = (const float*)d_in[21];
    const float* out_w    = (const float*)d_in[22];
    const float* out_b    = (const float*)d_in[23];
    float* out = (float*)d_out;

    float* ws    = (float*)d_ws;
    float* EW    = ws;                        // 1280
    float* BLR   = EW + 1280;                 // 512
    float* H0    = BLR + 512;                 // 768000
    float* HIN   = H0 + 768000;               // 768000
    int*   CNT   = (int*)(HIN + 768000);      // 6000
    float* EBS   = (float*)(CNT + 6000);      // 1536000
    f16*   BFh   = (f16*)(EBS + 1536000);     // 786432
    f16*   WTh   = BFh + 786432;              // 65536
    f16*   H0F   = WTh + 65536;               // 768000
    f16*   TF0   = H0F + 768000;              // 768000
    f16*   TF1   = TF0 + 768000;              // 768000
    f16*   XLXRh = TF1 + 768000;              // 1536000

    dim3 b256(256);
    hipMemsetAsync(CNT, 0, NN * sizeof(int), stream);
    hipLaunchKernelGGL(k_pre_all, dim3(3574), b256, 0, stream,
                       nn_w, nn_b, nn_root, BFh,
                       x, node_w, H0, H0F, ei, eattr, CNT, EBS,
                       gat_e_w, eew, eeb, gat_l_b, gat_r_b, EW, BLR,
                       gat_l_w, gat_r_w, WTh);

    for (int i = 0; i < 2; ++i) {
        hipLaunchKernelGGL(k_mm16, dim3(94, 4), b256, 0, stream,
                           H0F, WTh + i * 32768,
                           BLR + i * 256, XLXRh, NN, 256);
        hipLaunchKernelGGL(k_gat_fused, dim3(1500), b256, 0, stream,
                           XLXRh, EBS, CNT, EW + i * 640, gat_att + i * 128,
                           H0, gat_bias + i * 128, gat_ln_g + i * 128, gat_ln_b + i * 128,
                           (i == 0) ? H0F : TF0);
    }

    // conv chain: 9 launches, TF ping-pong
    hipLaunchKernelGGL(k_conv, dim3(1500), b256, 0, stream,
                       EBS, CNT, TF0, BFh, nn_bias,
                       H0, HIN, dec_g, dec_b, TF1, 0,
                       (const float*)nullptr, (const float*)nullptr, (float*)nullptr);

    for (int i = 0; i < 8; ++i) {
        int fin = (i == 7);
        const f16* tin  = (i & 1) ? TF0 : TF1;
        f16*       tout = (i & 1) ? TF1 : TF0;
        hipLaunchKernelGGL(k_conv, dim3(1500), b256, 0, stream,
                           EBS, CNT, tin,
                           BFh + (size_t)i * 98304,
                           nn_bias + i * 128, H0, HIN,
                           fin ? dec_g : dec_g + (i + 1) * 128,
                           fin ? dec_b : dec_b + (i + 1) * 128,
                           tout, fin ? 2 : 1, out_w, out_b, out);
    }
}

// Round 19
// 161.829 us; speedup vs baseline: 1.2362x; 1.2362x over previous
//
#include <hip/hip_runtime.h>
#include <math.h>

#define NN 6000
#define NE 12000
#define DCAP 32
// HC=128, H=4, D=32

typedef _Float16 f16;
typedef _Float16 f16x8 __attribute__((ext_vector_type(8)));
typedef unsigned short u16x8 __attribute__((ext_vector_type(8)));
typedef float f32x4 __attribute__((ext_vector_type(4)));

__device__ __forceinline__ float gelu_f(float x) {
    return 0.5f * x * (1.0f + erff(x * 0.70710678118654752f));
}

// ---------------- merged preamble ----------------
// blocks [0,512): pre_bmat -> fragment-major single-f16 BF
// blocks [512,3512): node_enc; [3512,3559): bucket; [3559,3566): pre_ew; [3566,3574): split_gat
// requires CNT pre-zeroed.
__global__ __launch_bounds__(256) void k_pre_all(
    const float* __restrict__ nn_w, const float* __restrict__ nn_b,
    const float* __restrict__ nn_root, f16* __restrict__ bfh,
    const float* __restrict__ x, const float* __restrict__ node_w,
    float* __restrict__ h0, f16* __restrict__ hf,
    const int* __restrict__ ei, const float* __restrict__ eattr,
    int* __restrict__ cnt, float* __restrict__ ebs,
    const float* __restrict__ gat_e_w, const float* __restrict__ eew,
    const float* __restrict__ eeb, const float* __restrict__ lb,
    const float* __restrict__ rb, float* __restrict__ EW, float* __restrict__ biasLR,
    const float* __restrict__ gwl, const float* __restrict__ gwr,
    f16* __restrict__ WTh)
{
    __shared__ float enc[5][128];
    int b = blockIdx.x;
    int tid = threadIdx.x;
    if (b < 512) {
        for (int l = tid; l < 640; l += 256) {
            int j = l >> 7, k = l & 127;
            enc[j][k] = (j < 4) ? eew[j * 128 + k] : eeb[k];
        }
        __syncthreads();
        int gid = b * 256 + tid;            // 8 * 16384 total
        int i = gid >> 14;
        int col = gid & 16383;              // k_in*128 + o
        int k_in = col >> 7, o = col & 127;
        const float* w = nn_w + (size_t)i * (128 * 16384) + col;
        float a0 = 0.f, a1 = 0.f, a2 = 0.f, a3 = 0.f, a4 = 0.f;
        #pragma unroll 8
        for (int k = 0; k < 128; ++k) {
            float wv = w[(size_t)k * 16384];
            a0 += enc[0][k] * wv; a1 += enc[1][k] * wv; a2 += enc[2][k] * wv;
            a3 += enc[3][k] * wv; a4 += enc[4][k] * wv;
        }
        a4 += nn_b[i * 16384 + col];
        float root = nn_root[(size_t)i * 16384 + col];
        float vals[6] = {a0, a1, a2, a3, a4, root};
        int ot = o >> 4, l15o = o & 15;
        size_t base_i = ((size_t)i * 8 + ot) * 24;
        #pragma unroll
        for (int j = 0; j < 6; ++j) {
            int c = j * 128 + k_in;
            int kb = c >> 5, lg = (c >> 3) & 3, jj = c & 7;
            size_t dst = ((base_i + kb) * 64 + lg * 16 + l15o) * 8 + jj;
            bfh[dst] = (f16)vals[j];
        }
    } else if (b < 3512) {
        int idx = (b - 512) * 256 + tid;
        int n = idx >> 7, c = idx & 127;
        float s = 0.f;
        #pragma unroll
        for (int f = 0; f < 6; ++f) s += x[n * 6 + f] * node_w[f * 128 + c];
        h0[idx] = s;
        hf[idx] = (f16)s;
    } else if (b < 3559) {
        int e = (b - 3512) * 256 + tid;
        if (e < NE) {
            int d = ei[NE + e];
            int pos = atomicAdd(&cnt[d], 1);
            if (pos < DCAP) {
                float* p = ebs + (size_t)(d * DCAP + pos) * 8;
                p[0] = __int_as_float(ei[e]);
                p[1] = eattr[e * 4 + 0];
                p[2] = eattr[e * 4 + 1];
                p[3] = eattr[e * 4 + 2];
                p[4] = eattr[e * 4 + 3];
            }
        }
    } else if (b < 3566) {
        int idx = (b - 3559) * 256 + tid;
        if (idx < 1280) {
            int i = idx / 640; int r = idx % 640; int j = r >> 7; int o = r & 127;
            float s = 0.f;
            for (int k = 0; k < 128; ++k) {
                float e = (j < 4) ? eew[j * 128 + k] : eeb[k];
                s += e * gat_e_w[i * 16384 + k * 128 + o];
            }
            EW[idx] = s;
        } else if (idx < 1792) {
            int j = idx - 1280; int i = j >> 8; int c = j & 255;
            biasLR[j] = (c < 128) ? lb[i * 128 + c] : rb[i * 128 + c - 128];
        }
    } else {
        int bb = b - 3566;              // 0..7
        int i = bb >> 2, half = (bb >> 1) & 1, piece = bb & 1;
        const float* s = (half ? gwr : gwl) + (size_t)i * 16384;
        size_t dbase = (size_t)i * 32768 + (size_t)half * 16384;
        for (int l = tid + piece * 8192; l < 8192 + piece * 8192; l += 256) {
            int o = l >> 7, k = l & 127;
            WTh[dbase + o * 128 + k] = (f16)s[k * 128 + o];
        }
    }
}

// ---------------- MFMA matmul (GAT): C[M,P](f16) = A_f16 @ B^T + bias ----------------
__global__ __launch_bounds__(256) void k_mm16(
    const f16* __restrict__ A, const f16* __restrict__ Bh,
    const float* __restrict__ bias, f16* __restrict__ C, int M, int P)
{
    __shared__ __align__(16) unsigned short smem[16384];   // 32KB: sA|sBh
    unsigned short* sA  = smem;
    unsigned short* sBh = smem + 8192;
    const int tid = threadIdx.x;
    const int r0 = blockIdx.x * 64, n0 = blockIdx.y * 64;
    #pragma unroll
    for (int i = 0; i < 4; ++i) {
        int g = tid + i * 256; int row = g >> 4, u = g & 15;
        int dst = row * 128 + ((u ^ (row & 7)) << 3);
        int r = r0 + row;
        if (r < M) *(u16x8*)&sA[dst] = *(const u16x8*)((const unsigned short*)A + (size_t)r * 128 + u * 8);
        else { u16x8 z; for (int j = 0; j < 8; ++j) z[j] = 0; *(u16x8*)&sA[dst] = z; }
        size_t sb = (size_t)(n0 + row) * 128 + u * 8;
        *(u16x8*)&sBh[dst] = *(const u16x8*)((const unsigned short*)Bh + sb);
    }
    __syncthreads();
    const int lane = tid & 63, wid = tid >> 6;
    const int wm = wid & 1, wn = wid >> 1;
    const int l15 = lane & 15, lg = lane >> 4;
    f32x4 acc[2][2] = {};
    #pragma unroll
    for (int kk = 0; kk < 4; ++kk) {
        f16x8 a[2], bh_[2];
        #pragma unroll
        for (int fm = 0; fm < 2; ++fm) {
            int row = wm * 32 + fm * 16 + l15;
            int off = row * 128 + ((((kk << 2) + lg) ^ (row & 7)) << 3);
            a[fm] = *(const f16x8*)&sA[off];
        }
        #pragma unroll
        for (int fn = 0; fn < 2; ++fn) {
            int row = wn * 32 + fn * 16 + l15;
            int off = row * 128 + ((((kk << 2) + lg) ^ (row & 7)) << 3);
            bh_[fn] = *(const f16x8*)&sBh[off];
        }
        #pragma unroll
        for (int fm = 0; fm < 2; ++fm)
        #pragma unroll
        for (int fn = 0; fn < 2; ++fn)
            acc[fm][fn] = __builtin_amdgcn_mfma_f32_16x16x32_f16(a[fm], bh_[fn], acc[fm][fn], 0, 0, 0);
    }
    #pragma unroll
    for (int fn = 0; fn < 2; ++fn) {
        int col = n0 + wn * 32 + fn * 16 + l15;
        float bv = bias ? bias[col] : 0.f;
        #pragma unroll
        for (int fm = 0; fm < 2; ++fm) {
            int rbase = r0 + wm * 32 + fm * 16 + lg * 4;
            #pragma unroll
            for (int j = 0; j < 4; ++j) {
                int r = rbase + j;
                if (r < M) C[(size_t)r * P + col] = (f16)(acc[fm][fn][j] + bv);
            }
        }
    }
}

// ---------------- fused GATv2 layer (f16 XLXR, batched loads + deg<=4 register cache) ----------------
__global__ __launch_bounds__(256) void k_gat_fused(
    const f16* __restrict__ XLXR, const float* __restrict__ ebs,
    const int* __restrict__ cnt, const float* __restrict__ EW,
    const float* __restrict__ att, float* __restrict__ h0,
    const float* __restrict__ bias, const float* __restrict__ g,
    const float* __restrict__ b,
    f16* __restrict__ hf)
{
    __shared__ float slog[4][DCAP][4];
    __shared__ float sms[4][4][2];
    int rowl = threadIdx.x >> 6, lane = threadIdx.x & 63;
    int r = blockIdx.x * 4 + rowl;
    int deg = cnt[r]; if (deg > DCAP) deg = DCAP;
    int dc = (deg < 4) ? deg : 4;
    float hz0 = h0[r * 128 + lane], hz1 = h0[r * 128 + 64 + lane];
    float xr0 = (float)XLXR[r * 256 + 128 + lane];
    float xr1 = (float)XLXR[r * 256 + 192 + lane];
    float e0 = EW[lane], e1 = EW[128 + lane], e2 = EW[256 + lane], e3 = EW[384 + lane], e4 = EW[512 + lane];
    float f0 = EW[64 + lane], f1 = EW[192 + lane], f2 = EW[320 + lane], f3 = EW[448 + lane], f4 = EW[576 + lane];
    float at0 = att[lane], at1 = att[64 + lane];
    f32x4 q[4]; float a3v[4]; float xs0[4], xs1[4];
    #pragma unroll
    for (int j = 0; j < 4; ++j) {
        if (j < dc) {
            const float* ep = ebs + (size_t)(r * DCAP + j) * 8;
            q[j] = *(const f32x4*)ep;
            a3v[j] = ep[4];
        }
    }
    #pragma unroll
    for (int j = 0; j < 4; ++j) {
        if (j < dc) {
            int s = __float_as_int(q[j][0]);
            xs0[j] = (float)XLXR[s * 256 + lane];
            xs1[j] = (float)XLXR[s * 256 + 64 + lane];
        }
    }
    #pragma unroll
    for (int j = 0; j < 4; ++j) {
        if (j < dc) {
            float a0 = q[j][1], a1 = q[j][2], a2 = q[j][3], a3 = a3v[j];
            float g0 = xs0[j] + xr0 + (a0 * e0 + a1 * e1 + a2 * e2 + a3 * e3 + e4);
            float g1 = xs1[j] + xr1 + (a0 * f0 + a1 * f1 + a2 * f2 + a3 * f3 + f4);
            g0 = (g0 > 0.f) ? g0 : 0.1f * g0;
            g1 = (g1 > 0.f) ? g1 : 0.1f * g1;
            float p0 = g0 * at0, p1 = g1 * at1;
            for (int o = 16; o; o >>= 1) { p0 += __shfl_xor(p0, o, 32); p1 += __shfl_xor(p1, o, 32); }
            if ((lane & 31) == 0) {
                int hh2 = lane >> 5;
                slog[rowl][j][hh2] = p0;
                slog[rowl][j][2 + hh2] = p1;
            }
        }
    }
    for (int k = 4; k < deg; ++k) {
        const float* ep = ebs + (size_t)(r * DCAP + k) * 8;
        f32x4 qq = *(const f32x4*)ep;
        float a3 = ep[4];
        int s = __float_as_int(qq[0]);
        float a0 = qq[1], a1 = qq[2], a2 = qq[3];
        float g0 = (float)XLXR[s * 256 + lane]      + xr0 + (a0 * e0 + a1 * e1 + a2 * e2 + a3 * e3 + e4);
        float g1 = (float)XLXR[s * 256 + 64 + lane] + xr1 + (a0 * f0 + a1 * f1 + a2 * f2 + a3 * f3 + f4);
        g0 = (g0 > 0.f) ? g0 : 0.1f * g0;
        g1 = (g1 > 0.f) ? g1 : 0.1f * g1;
        float p0 = g0 * at0, p1 = g1 * at1;
        for (int o = 16; o; o >>= 1) { p0 += __shfl_xor(p0, o, 32); p1 += __shfl_xor(p1, o, 32); }
        if ((lane & 31) == 0) {
            int hh2 = lane >> 5;
            slog[rowl][k][hh2] = p0;
            slog[rowl][k][2 + hh2] = p1;
        }
    }
    if (lane < 4) {
        float mh = -1e30f;
        for (int k = 0; k < deg; ++k) mh = fmaxf(mh, slog[rowl][k][lane]);
        float sh = 0.f;
        for (int k = 0; k < deg; ++k) sh += expf(slog[rowl][k][lane] - mh);
        sms[rowl][lane][0] = mh; sms[rowl][lane][1] = sh;
    }
    int hd = lane >> 5;
    float m0 = sms[rowl][hd][0], s0 = sms[rowl][hd][1];
    float m1 = sms[rowl][2 + hd][0], s1 = sms[rowl][2 + hd][1];
    float acc0 = 0.f, acc1 = 0.f;
    #pragma unroll
    for (int j = 0; j < 4; ++j) {
        if (j < dc) {
            float al0 = expf(slog[rowl][j][hd] - m0) / (s0 + 1e-16f);
            float al1 = expf(slog[rowl][j][2 + hd] - m1) / (s1 + 1e-16f);
            acc0 += al0 * xs0[j];
            acc1 += al1 * xs1[j];
        }
    }
    for (int k = 4; k < deg; ++k) {
        int s = __float_as_int(ebs[(size_t)(r * DCAP + k) * 8]);
        float al0 = expf(slog[rowl][k][hd] - m0) / (s0 + 1e-16f);
        float al1 = expf(slog[rowl][k][2 + hd] - m1) / (s1 + 1e-16f);
        acc0 += al0 * (float)XLXR[s * 256 + lane];
        acc1 += al1 * (float)XLXR[s * 256 + 64 + lane];
    }
    float v0 = hz0 + acc0 + bias[lane];
    float v1 = hz1 + acc1 + bias[64 + lane];
    float sum = v0 + v1;
    for (int o = 32; o; o >>= 1) sum += __shfl_xor(sum, o, 64);
    float mean = sum * 0.0078125f;
    float d0 = v0 - mean, d1 = v1 - mean;
    float var = d0 * d0 + d1 * d1;
    for (int o = 32; o; o >>= 1) var += __shfl_xor(var, o, 64);
    float inv = rsqrtf(var * 0.0078125f + 1e-5f);
    float y0 = gelu_f(d0 * inv * g[lane] + b[lane]);
    float y1 = gelu_f(d1 * inv * g[64 + lane] + b[64 + lane]);
    h0[r * 128 + lane] = y0; h0[r * 128 + 64 + lane] = y1;
    hf[r * 128 + lane] = (f16)y0;
    hf[r * 128 + 64 + lane] = (f16)y1;
}

// ---------------- fused NNConv layer (BM=8, grid 750, 512 thr), single-f16 B ----------------
// each wave owns ONE dst row: single 2-level gather chain per wave; rows 8..15 zero-padded.
__global__ __launch_bounds__(512) void k_conv(
    const float* __restrict__ ebs, const int* __restrict__ cnt,
    const f16* __restrict__ TF,
    const f16* __restrict__ BFh,
    const float* __restrict__ bias,
    const float* __restrict__ h0, float* __restrict__ HIN,
    const float* __restrict__ lng, const float* __restrict__ lnb,
    f16* __restrict__ TFout, int kind,
    const float* __restrict__ outw, const float* __restrict__ outb,
    float* __restrict__ outp)
{
    __shared__ __align__(16) unsigned short sA[16 * 768];   // 24KB (rows 8..15 zero)
    const int tid = threadIdx.x;
    const int r0 = blockIdx.x * 8;
    const int lane = tid & 63, w = tid >> 6;
    const int l15 = lane & 15, lg = lane >> 4;

    // zero pad rows 8..15 (wave w -> row 8+w)
    {
        unsigned int* zp = (unsigned int*)&sA[(8 + w) * 768];
        #pragma unroll
        for (int z = 0; z < 6; ++z) zp[lane + z * 64] = 0;
    }

    // ---- phase 1: single-row batched gather + epilogue prefetch ----
    int r = r0 + w;
    int deg = cnt[r]; if (deg > DCAP) deg = DCAP;   // r < 6000 always (grid 750*8)
    float bs0 = bias[lane], bs1 = bias[64 + lane];
    float lg0 = lng[lane], lg1 = lng[64 + lane];
    float lb0 = lnb[lane], lb1 = lnb[64 + lane];
    float h00 = 0.f, h01 = 0.f, hi0 = 0.f, hi1 = 0.f;
    if (kind != 2) {
        h00 = h0[r * 128 + lane];
        h01 = h0[r * 128 + 64 + lane];
    }
    if (kind != 0) {
        hi0 = HIN[r * 128 + lane];
        hi1 = HIN[r * 128 + 64 + lane];
    }
    unsigned int rtv = *(const unsigned int*)&TF[(size_t)r * 128 + lane * 2];
    float acc[5][2] = {};
    for (int k0 = 0; k0 < deg; k0 += 4) {
        int km = deg - k0; if (km > 4) km = 4;
        f32x4 q[4]; float a3v[4]; unsigned int tt[4];
        #pragma unroll
        for (int j = 0; j < 4; ++j) {
            if (j < km) {
                const float* ep = ebs + (size_t)(r * DCAP + k0 + j) * 8;
                q[j] = *(const f32x4*)ep;
                a3v[j] = ep[4];
            }
        }
        #pragma unroll
        for (int j = 0; j < 4; ++j) {
            if (j < km) {
                int s = __float_as_int(q[j][0]);
                tt[j] = *(const unsigned int*)&TF[(size_t)s * 128 + lane * 2];
            }
        }
        #pragma unroll
        for (int j = 0; j < 4; ++j) {
            if (j < km) {
                float a0 = q[j][1], a1 = q[j][2], a2 = q[j][3], a3 = a3v[j];
                float t0 = (float)__builtin_bit_cast(f16, (unsigned short)(tt[j] & 0xffff));
                float t1 = (float)__builtin_bit_cast(f16, (unsigned short)(tt[j] >> 16));
                acc[0][0] += a0 * t0; acc[1][0] += a1 * t0; acc[2][0] += a2 * t0;
                acc[3][0] += a3 * t0; acc[4][0] += t0;
                acc[0][1] += a0 * t1; acc[1][1] += a1 * t1; acc[2][1] += a2 * t1;
                acc[3][1] += a3 * t1; acc[4][1] += t1;
            }
        }
    }
    {
        int row = w;
        int rw = row & 7;
        #pragma unroll
        for (int j = 0; j < 5; ++j) {
            int u = j * 16 + (lane >> 2);
            int us = (u & ~7) | ((u & 7) ^ rw);
            unsigned short p0 = __builtin_bit_cast(unsigned short, (f16)acc[j][0]);
            unsigned short p1 = __builtin_bit_cast(unsigned short, (f16)acc[j][1]);
            *(unsigned int*)&sA[row * 768 + us * 8 + ((2 * lane) & 7)] =
                (unsigned int)p0 | ((unsigned int)p1 << 16);
        }
        int u = 80 + (lane >> 2);
        int us = (u & ~7) | ((u & 7) ^ rw);
        *(unsigned int*)&sA[row * 768 + us * 8 + ((2 * lane) & 7)] = rtv;
    }
    __syncthreads();

    // ---- phase 2: MFMA, wave w -> 16-col tile ot=w (rows 8..15 of A are zero) ----
    f32x4 acc2 = {};
    const f16* bhp = BFh + ((size_t)w * 24) * 512 + (size_t)lane * 8;
    #pragma unroll
    for (int kb = 0; kb < 24; ++kb) {
        f16x8 bhv = *(const f16x8*)(bhp + (size_t)kb * 512);
        int row = l15;
        int u = kb * 4 + lg;
        int us = (u & ~7) | ((u & 7) ^ (row & 7));
        f16x8 a = *(const f16x8*)&sA[row * 768 + us * 8];
        acc2 = __builtin_amdgcn_mfma_f32_16x16x32_f16(a, bhv, acc2, 0, 0, 0);
    }
    __syncthreads();
    float* sOut = (float*)sA;   // 8 x 132 f32, aliases sA
    {
        int col = w * 16 + l15;
        #pragma unroll
        for (int j = 0; j < 4; ++j) {
            int row = lg * 4 + j;
            if (row < 8) sOut[row * 132 + col] = acc2[j];
        }
    }
    __syncthreads();

    // ---- phase 3: epilogue, wave w -> its own row (prefetched inputs) ----
    {
        float c0 = bs0 + sOut[w * 132 + lane];
        float c1 = bs1 + sOut[w * 132 + 64 + lane];
        float u0, u1;
        if (kind == 0) {
            u0 = h00 + c0;
            u1 = h01 + c1;
            HIN[r * 128 + lane] = u0; HIN[r * 128 + 64 + lane] = u1;
        } else if (kind == 1) {
            u0 = hi0 + h00 + c0;
            u1 = hi1 + h01 + c1;
            HIN[r * 128 + lane] = u0; HIN[r * 128 + 64 + lane] = u1;
        } else {
            u0 = hi0 + c0;
            u1 = hi1 + c1;
        }
        float sum = u0 + u1;
        for (int o = 32; o; o >>= 1) sum += __shfl_xor(sum, o, 64);
        float mean = sum * 0.0078125f;
        float d0 = u0 - mean, d1 = u1 - mean;
        float var = d0 * d0 + d1 * d1;
        for (int o = 32; o; o >>= 1) var += __shfl_xor(var, o, 64);
        float inv = rsqrtf(var * 0.0078125f + 1e-5f);
        float y0 = gelu_f(d0 * inv * lg0 + lb0);
        float y1 = gelu_f(d1 * inv * lg1 + lb1);
        if (kind != 2) {
            TFout[r * 128 + lane] = (f16)y0;
            TFout[r * 128 + 64 + lane] = (f16)y1;
        } else {
            float p0 = y0 * outw[lane * 2 + 0] + y1 * outw[(64 + lane) * 2 + 0];
            float p1 = y0 * outw[lane * 2 + 1] + y1 * outw[(64 + lane) * 2 + 1];
            for (int o = 32; o; o >>= 1) { p0 += __shfl_xor(p0, o, 64); p1 += __shfl_xor(p1, o, 64); }
            if (lane == 0) {
                outp[r * 2 + 0] = p0 + outb[0];
                outp[r * 2 + 1] = p1 + outb[1];
            }
        }
    }
}

extern "C" void kernel_launch(void* const* d_in, const int* in_sizes, int n_in,
                              void* d_out, int out_size, void* d_ws, size_t ws_size,
                              hipStream_t stream)
{
    const float* x        = (const float*)d_in[0];
    const int*   ei       = (const int*)d_in[1];
    const float* eattr    = (const float*)d_in[2];
    const float* node_w   = (const float*)d_in[4];
    const float* eew      = (const float*)d_in[5];
    const float* eeb      = (const float*)d_in[6];
    const float* gat_l_w  = (const float*)d_in[7];
    const float* gat_l_b  = (const float*)d_in[8];
    const float* gat_r_w  = (const float*)d_in[9];
    const float* gat_r_b  = (const float*)d_in[10];
    const float* gat_e_w  = (const float*)d_in[11];
    const float* gat_att  = (const float*)d_in[12];
    const float* gat_bias = (const float*)d_in[13];
    const float* gat_ln_g = (const float*)d_in[14];
    const float* gat_ln_b = (const float*)d_in[15];
    const float* nn_w     = (const float*)d_in[16];
    const float* nn_b     = (const float*)d_in[17];
    const float* nn_root  = (const float*)d_in[18];
    const float* nn_bias  = (const float*)d_in[19];
    const float* dec_g    = (const float*)d_in[20];
    const float* dec_b    = (const float*)d_in[21];
    const float* out_w    = (const float*)d_in[22];
    const float* out_b    = (const float*)d_in[23];
    float* out = (float*)d_out;

    float* ws    = (float*)d_ws;
    float* EW    = ws;                        // 1280
    float* BLR   = EW + 1280;                 // 512
    float* H0    = BLR + 512;                 // 768000
    float* HIN   = H0 + 768000;               // 768000
    int*   CNT   = (int*)(HIN + 768000);      // 6000
    float* EBS   = (float*)(CNT + 6000);      // 1536000
    f16*   BFh   = (f16*)(EBS + 1536000);     // 786432
    f16*   WTh   = BFh + 786432;              // 65536
    f16*   H0F   = WTh + 65536;               // 768000
    f16*   TF0   = H0F + 768000;              // 768000
    f16*   TF1   = TF0 + 768000;              // 768000
    f16*   XLXRh = TF1 + 768000;              // 1536000

    dim3 b256(256), b512(512);
    hipMemsetAsync(CNT, 0, NN * sizeof(int), stream);
    hipLaunchKernelGGL(k_pre_all, dim3(3574), b256, 0, stream,
                       nn_w, nn_b, nn_root, BFh,
                       x, node_w, H0, H0F, ei, eattr, CNT, EBS,
                       gat_e_w, eew, eeb, gat_l_b, gat_r_b, EW, BLR,
                       gat_l_w, gat_r_w, WTh);

    for (int i = 0; i < 2; ++i) {
        hipLaunchKernelGGL(k_mm16, dim3(94, 4), b256, 0, stream,
                           H0F, WTh + i * 32768,
                           BLR + i * 256, XLXRh, NN, 256);
        hipLaunchKernelGGL(k_gat_fused, dim3(1500), b256, 0, stream,
                           XLXRh, EBS, CNT, EW + i * 640, gat_att + i * 128,
                           H0, gat_bias + i * 128, gat_ln_g + i * 128, gat_ln_b + i * 128,
                           (i == 0) ? H0F : TF0);
    }

    // conv chain: 9 launches, TF ping-pong
    hipLaunchKernelGGL(k_conv, dim3(750), b512, 0, stream,
                       EBS, CNT, TF0, BFh, nn_bias,
                       H0, HIN, dec_g, dec_b, TF1, 0,
                       (const float*)nullptr, (const float*)nullptr, (float*)nullptr);

    for (int i = 0; i < 8; ++i) {
        int fin = (i == 7);
        const f16* tin  = (i & 1) ? TF0 : TF1;
        f16*       tout = (i & 1) ? TF1 : TF0;
        hipLaunchKernelGGL(k_conv, dim3(750), b512, 0, stream,
                           EBS, CNT, tin,
                           BFh + (size_t)i * 98304,
                           nn_bias + i * 128, H0, HIN,
                           fin ? dec_g : dec_g + (i + 1) * 128,
                           fin ? dec_b : dec_b + (i + 1) * 128,
                           tout, fin ? 2 : 1, out_w, out_b, out);
    }
}